// Round 18
// baseline (3018.289 us; speedup 1.0000x reference)
//
#include <hip/hip_runtime.h>
#include <hip/hip_bf16.h>

#define SEQ_   128
#define NCLS_  50257
#define EMB_   1024
#define HID_   1024
#define BATCH_ 1024
#define G4_    4096

typedef __attribute__((ext_vector_type(8))) short short8;
typedef __attribute__((ext_vector_type(4))) float f32x4;

__device__ __forceinline__ void async_copy16(void* lds, const void* g) {
  __builtin_amdgcn_global_load_lds(
      (const __attribute__((address_space(1))) void*)g,
      (__attribute__((address_space(3))) void*)lds, 16, 0, 0);
}

#define MFMA_ACC(c, a, b) \
  (c) = __builtin_amdgcn_mfma_f32_16x16x32_bf16((a), (b), (c), 0, 0, 0)

#define CFENCE() asm volatile("" ::: "memory")

__device__ __forceinline__ float sigmoidf_(float x) {
  return 1.f / (1.f + __expf(-x));
}
__device__ __forceinline__ float tanhf_(float x) {
  x = fminf(12.f, fmaxf(-12.f, x));
  float e = __expf(2.f * x);
  return (e - 1.f) / (e + 1.f);
}
__device__ __forceinline__ float bf2f_(ushort u) {
  return __uint_as_float(((unsigned int)u) << 16);
}

// ---------------------------------------------------------------------------
// MFMA GEMM (r4 structure, builtin MFMA): C = A[M,K] x Bt[N,K], k-XOR-
// swizzled rows, BK=64 double-buffered, counted vmcnt(8), 256 thr / 4 waves.
// EPI 0: outB = bf16(acc + bias0[col]); LDS-repacked epilogue (stride 136)
//        -> 16B/lane full-row stores.
// EPI 2: outF = acc + bias0[col]; LDS-repacked [64][132] f32 half-tiles
//        -> full-row coalesced dword stores.
// ---------------------------------------------------------------------------
template <int EPI>
__global__ __launch_bounds__(256) void gemm_bt(
    const __hip_bfloat16* __restrict__ A, const __hip_bfloat16* __restrict__ Bt,
    float* __restrict__ outF, __hip_bfloat16* __restrict__ outB,
    int Mreal, int Nreal, int K, long ostride,
    const float* __restrict__ bias0) {
  __shared__ __align__(16) char smem[65536];

  const int tid = threadIdx.x;
  const int lane = tid & 63;
  const int w = tid >> 6;
  const int wm = w >> 1;
  const int wn = w & 1;
  const int m0 = blockIdx.y * 128;
  const int n0 = blockIdx.x * 128;

  const int fr = lane & 15;
  const int kb = (lane >> 4) * 16;
  const int swz = (fr & 7) << 4;

  f32x4 acc[4][4];
#pragma unroll
  for (int i = 0; i < 4; ++i)
#pragma unroll
    for (int j = 0; j < 4; ++j) acc[i][j] = (f32x4)(0.0f);

  auto STAGE = [&](int kc, int b) {
#pragma unroll
    for (int q = 0; q < 8; ++q) {
      const int ridx = (q & 3) * 256 + tid;
      const int row = ridx >> 3;
      const int ch = ridx & 7;
      const __hip_bfloat16* src;
      char* dst;
      if (q < 4) {
        long ar = m0 + row; if (ar >= Mreal) ar = Mreal - 1;
        src = A + ar * (long)K + kc * 64 + ch * 8;
        dst = smem + b * 16384 + ridx * 16;
      } else {
        long br = n0 + row; if (br >= Nreal) br = Nreal - 1;
        src = Bt + br * (long)K + kc * 64 + ch * 8;
        dst = smem + 32768 + b * 16384 + ridx * 16;
      }
      async_copy16(dst, src);
    }
  };

  const int KC = K >> 6;
  STAGE(0, 0);
  for (int kc = 0; kc < KC; ++kc) {
    const int b = kc & 1;
    if (kc + 1 < KC) {
      STAGE(kc + 1, b ^ 1);
      asm volatile("s_waitcnt vmcnt(8)" ::: "memory");
    } else {
      asm volatile("s_waitcnt vmcnt(0)" ::: "memory");
    }
    __builtin_amdgcn_s_barrier();
    CFENCE();

    short8 aR[2][4], bR[2][4];
#pragma unroll
    for (int kk = 0; kk < 2; ++kk)
#pragma unroll
      for (int f = 0; f < 4; ++f) {
        aR[kk][f] = *(const short8*)(smem + b * 16384 +
                     (wm * 64 + f * 16 + fr) * 128 + ((kk * 64 + kb) ^ swz));
        bR[kk][f] = *(const short8*)(smem + 32768 + b * 16384 +
                     (wn * 64 + f * 16 + fr) * 128 + ((kk * 64 + kb) ^ swz));
      }
#pragma unroll
    for (int fm = 0; fm < 4; ++fm)
#pragma unroll
      for (int fn = 0; fn < 4; ++fn) {
        MFMA_ACC(acc[fm][fn], aR[0][fm], bR[0][fn]);
        MFMA_ACC(acc[fm][fn], aR[1][fm], bR[1][fn]);
      }
    CFENCE();
    __builtin_amdgcn_s_barrier();
  }

  const int cn = lane & 15;
  const int rb = (lane >> 4) * 4;

  if (EPI == 0) {
    __hip_bfloat16* ldsC = (__hip_bfloat16*)smem;  // [128][136] bf16
#pragma unroll
    for (int fn = 0; fn < 4; ++fn) {
      const int col = wn * 64 + fn * 16 + cn;
      const float badd = bias0[n0 + col];
#pragma unroll
      for (int fm = 0; fm < 4; ++fm)
#pragma unroll
        for (int r = 0; r < 4; ++r)
          ldsC[(wm * 64 + fm * 16 + rb + r) * 136 + col] =
              __float2bfloat16(acc[fm][fn][r] + badd);
    }
    __syncthreads();
#pragma unroll
    for (int q = 0; q < 8; ++q) {
      const int chunk = q * 256 + tid;      // 0..2047 (128 rows x 16 chunks)
      const int row = chunk >> 4;
      const int c8 = (chunk & 15) * 8;
      if (m0 + row < Mreal)
        *(short8*)(outB + (long)(m0 + row) * ostride + n0 + c8) =
            *(const short8*)(ldsC + row * 136 + c8);
    }
  } else {
    float* ldsC = (float*)smem;  // [64][132] f32
#pragma unroll
    for (int half = 0; half < 2; ++half) {
      __syncthreads();
      if (wm == half) {
#pragma unroll
        for (int fn = 0; fn < 4; ++fn) {
          const int col = wn * 64 + fn * 16 + cn;
          const int gc = n0 + col;
          const float badd = (gc < Nreal) ? bias0[gc] : 0.f;
#pragma unroll
          for (int fm = 0; fm < 4; ++fm)
#pragma unroll
            for (int r = 0; r < 4; ++r)
              ldsC[(fm * 16 + rb + r) * 132 + col] = acc[fm][fn][r] + badd;
        }
      }
      __syncthreads();
#pragma unroll
      for (int it = 0; it < 32; ++it) {
        const int idx = it * 256 + tid;   // 0..8191 (64 rows x 128 cols)
        const int row = idx >> 7;
        const int col = idx & 127;
        const int grow = m0 + half * 64 + row;
        const int gcol = n0 + col;
        if (grow < Mreal && gcol < Nreal)
          outF[(long)grow * ostride + gcol] = ldsC[row * 132 + col];
      }
    }
  }
}

// ---------------------------------------------------------------------------
// Wh pack (r7 layout): tile = ((ht*2+wn)*2+kh)*64 + kc*8 + kk*4 + g.
// ---------------------------------------------------------------------------
__global__ __launch_bounds__(256) void pack_b(const float* __restrict__ Wh,
                                              __hip_bfloat16* __restrict__ Bpk) {
  const int gtid = blockIdx.x * 256 + threadIdx.x;  // 0..524287
  const int l = gtid & 63;
  const int tile = gtid >> 6;                       // 0..8191
  const int g = tile & 3;
  const int kk = (tile >> 2) & 1;
  const int kc = (tile >> 3) & 7;
  const int kh = (tile >> 6) & 1;
  const int wn = (tile >> 7) & 1;
  const int ht = tile >> 8;
  const int h = ht * 32 + wn * 16 + (l & 15);
  const int k0 = kh * 512 + kc * 64 + kk * 32 + (l >> 4) * 8;
  short8 v;
#pragma unroll
  for (int e = 0; e < 8; ++e) {
    const __hip_bfloat16 b = __float2bfloat16(Wh[(size_t)(k0 + e) * G4_ + g * 1024 + h]);
    v[e] = *reinterpret_cast<const short*>(&b);
  }
  *(short8*)(Bpk + (size_t)gtid * 8) = v;
}

// ---------------------------------------------------------------------------
// Fused LSTM step (r7 structure, builtin MFMA). Grid 256, 512 threads,
// 96 KB dynamic LDS (3 x 32KB A bufs), B direct-to-register from Bpk.
// Eps/c/token loads issued BEFORE the K-loop -> gather latency hides under
// ~12 us of GEMM instead of sitting serially before the cell phase.
// ---------------------------------------------------------------------------
__global__ __launch_bounds__(512, 2) void lstm_step(
    const __hip_bfloat16* __restrict__ hprev,   // [1024][1024] swizzled
    const __hip_bfloat16* __restrict__ Bpk,     // packed Wh (8 MB)
    const __hip_bfloat16* __restrict__ Epr,     // [V][4096] col=4h+g
    const int* __restrict__ X,
    float* __restrict__ cbuf,                   // [1024][1024] f32
    __hip_bfloat16* __restrict__ hnext,         // swizzled
    int t) {
  extern __shared__ __align__(16) char smem[];  // 98304 = 3 x 32KB A bufs
  float* gacc = (float*)smem;                   // [128][132] f32 (aliases)

  const int tid = threadIdx.x;
  const int lane = tid & 63;
  const int w = tid >> 6;
  const int wm = (w >> 1) & 1;
  const int wn = w & 1;
  const int kh = w >> 2;
  const int bid = blockIdx.x;
  const int xcd = bid & 7;
  const int j = bid >> 3;
  const int ht = xcd * 4 + (j & 3);   // Bpk slice pinned to one XCD's L2
  const int mt = j >> 2;
  const int m0 = mt * 128;
  const int h0 = ht * 32;

  const int fr = lane & 15;
  const int kb = (lane >> 4) * 16;
  const int swz = (fr & 7) << 4;
  const int cn = lane & 15;
  const int rb = (lane >> 4) * 4;

  const int crow = tid >> 2;
  const int hq = tid & 3;
  const int prow = m0 + crow;
  const int tok1 = X[prow * SEQ_ + t];

  const __hip_bfloat16* bb =
      Bpk + (size_t)(((ht * 2 + wn) * 2 + kh) * 64) * 512 + lane * 8;

  // ---- prefetch Eps gather + c state BEFORE the K-loop (latency hidden)
  ushort4 ep[8];
  float cold[8];
#pragma unroll
  for (int jj = 0; jj < 8; ++jj) {
    ep[jj] = *(const ushort4*)(Epr + (size_t)tok1 * G4_ + (h0 + hq * 8 + jj) * 4);
    cold[jj] = cbuf[(size_t)prow * HID_ + h0 + hq * 8 + jj];
  }
  CFENCE();

  f32x4 acc[4][4];  // [fm][gate]
#pragma unroll
  for (int i = 0; i < 4; ++i)
#pragma unroll
    for (int g = 0; g < 4; ++g) acc[i][g] = (f32x4)(0.0f);

  auto STAGE_A = [&](int kc, int b) {
#pragma unroll
    for (int q = 0; q < 4; ++q) {
      const int region = q >> 1;           // kh-half
      const int r = (q & 1) * 512 + tid;   // 0..1023 chunks
      const int row = r >> 3, ch = r & 7;
      const __hip_bfloat16* src =
          hprev + (size_t)(m0 + row) * HID_ + region * 512 + kc * 64 + ch * 8;
      async_copy16(smem + b * 32768 + region * 16384 + r * 16, src);
    }
  };

  short8 bR[2][2][4];  // [kc&1][kk][g]

  STAGE_A(0, 0);
#pragma unroll
  for (int kk = 0; kk < 2; ++kk)
#pragma unroll
    for (int g = 0; g < 4; ++g)
      bR[0][kk][g] = *(const short8*)(bb + (0 * 8 + kk * 4 + g) * 512);
  STAGE_A(1, 1);

#pragma unroll
  for (int kc = 0; kc < 8; ++kc) {
    __builtin_amdgcn_s_barrier();
    CFENCE();
    if (kc + 1 < 8) {
#pragma unroll
      for (int kk = 0; kk < 2; ++kk)
#pragma unroll
        for (int g = 0; g < 4; ++g)
          bR[(kc + 1) & 1][kk][g] =
              *(const short8*)(bb + ((kc + 1) * 8 + kk * 4 + g) * 512);
    }
    if (kc + 2 < 8) STAGE_A(kc + 2, (kc + 2) % 3);
    // vmcnt accounting shifted by the 16 prologue ep/cold loads having
    // completed long before (they are oldest; counts below still conservative)
    if (kc < 6)      asm volatile("s_waitcnt vmcnt(24)" ::: "memory");
    else if (kc == 6) asm volatile("s_waitcnt vmcnt(20)" ::: "memory");
    else             asm volatile("s_waitcnt vmcnt(8)" ::: "memory");
    CFENCE();

    const char* baseA = smem + (kc % 3) * 32768 + kh * 16384;
    short8 aR[2][4];
#pragma unroll
    for (int kk = 0; kk < 2; ++kk)
#pragma unroll
      for (int f = 0; f < 4; ++f)
        aR[kk][f] = *(const short8*)(baseA + (wm * 64 + f * 16 + fr) * 128 +
                                     ((kk * 64 + kb) ^ swz));
    __builtin_amdgcn_s_setprio(1);
#pragma unroll
    for (int fm = 0; fm < 4; ++fm)
#pragma unroll
      for (int g = 0; g < 4; ++g) {
        MFMA_ACC(acc[fm][g], aR[0][fm], bR[kc & 1][0][g]);
        MFMA_ACC(acc[fm][g], aR[1][fm], bR[kc & 1][1][g]);
      }
    __builtin_amdgcn_s_setprio(0);
    CFENCE();
  }

  __syncthreads();
  if (kh == 0) {
#pragma unroll
    for (int fm = 0; fm < 4; ++fm)
#pragma unroll
      for (int g = 0; g < 4; ++g)
#pragma unroll
        for (int r = 0; r < 4; ++r)
          gacc[(wm * 64 + fm * 16 + rb + r) * 132 + (wn * 16 + cn) * 4 + g] =
              acc[fm][g][r];
  }
  __syncthreads();
  if (kh == 1) {
#pragma unroll
    for (int fm = 0; fm < 4; ++fm)
#pragma unroll
      for (int g = 0; g < 4; ++g)
#pragma unroll
        for (int r = 0; r < 4; ++r)
          gacc[(wm * 64 + fm * 16 + rb + r) * 132 + (wn * 16 + cn) * 4 + g] +=
              acc[fm][g][r];
  }
  __syncthreads();

  const float* gr = gacc + crow * 132 + hq * 32;
  f32x4 cnew0, cnew1;
  short8 hv;
#pragma unroll
  for (int jj = 0; jj < 8; ++jj) {
    const f32x4 g4 = *(const f32x4*)(gr + jj * 4);
    const float iv = sigmoidf_(g4[0] + bf2f_(ep[jj].x));
    const float fv = sigmoidf_(g4[1] + bf2f_(ep[jj].y));
    const float gv = tanhf_(g4[2] + bf2f_(ep[jj].z));
    const float ov = sigmoidf_(g4[3] + bf2f_(ep[jj].w));
    const float cv = fv * cold[jj] + iv * gv;
    if (jj < 4) cnew0[jj] = cv; else cnew1[jj - 4] = cv;
    const float hval = ov * tanhf_(cv);
    const __hip_bfloat16 hb = __float2bfloat16(hval);
    hv[jj] = *reinterpret_cast<const short*>(&hb);
  }
  float* cdst = cbuf + (size_t)prow * HID_ + h0 + hq * 8;
  *(f32x4*)cdst = cnew0;
  *(f32x4*)(cdst + 4) = cnew1;
  const int hcolb = h0 + hq * 8;
  const int hswb = (hcolb & ~63) | ((hcolb & 63) ^ ((prow & 7) << 3));
  *(short8*)(hnext + (size_t)prow * HID_ + hswb) = hv;
}

// fp32 -> bf16 flat convert; SWZ: k-XOR-swizzle per 64-col group (1024 cols)
template <bool SWZ>
__global__ __launch_bounds__(256) void conv_bf16_k(const float* __restrict__ in,
                                                   __hip_bfloat16* __restrict__ out, int n4) {
  const int i = blockIdx.x * 256 + threadIdx.x;
  if (i >= n4) return;
  const float4 v = ((const float4*)in)[i];
  int o = i * 4;
  if (SWZ) {
    const int row = o >> 10, col = o & 1023;
    const int cs = (col & ~63) | ((col & 63) ^ ((row & 7) << 3));
    o = (o & ~1023) | cs;
  }
  out[o + 0] = __float2bfloat16(v.x);
  out[o + 1] = __float2bfloat16(v.y);
  out[o + 2] = __float2bfloat16(v.z);
  out[o + 3] = __float2bfloat16(v.w);
}

// in[R][C] fp32 -> out[C][R] bf16; PERM: gate-interleave out-rows (4h+g);
// SWZ: XOR-swizzle k per 64-group by out-row&7.
template <bool PERM, bool SWZ>
__global__ __launch_bounds__(256) void transpose_conv(const float* __restrict__ in,
                                                      __hip_bfloat16* __restrict__ out,
                                                      int R, int C) {
  __shared__ float tile[32][33];
  const int c0 = blockIdx.x * 32, r0 = blockIdx.y * 32;
  const int tx = threadIdx.x, ty = threadIdx.y;  // 32x8
#pragma unroll
  for (int i = 0; i < 4; ++i) {
    const int r = r0 + ty + i * 8, cc = c0 + tx;
    tile[ty + i * 8][tx] = (r < R && cc < C) ? in[(size_t)r * C + cc] : 0.f;
  }
  __syncthreads();
#pragma unroll
  for (int i = 0; i < 4; ++i) {
    const int ro = c0 + ty + i * 8, co = r0 + tx;
    if (ro < C && co < R) {
      const int n = PERM ? ((ro & 1023) * 4 + (ro >> 10)) : ro;
      int k = co;
      if (SWZ) k = (k & ~63) | ((k & 63) ^ ((n & 7) << 3));
      out[(size_t)n * R + k] = __float2bfloat16(tile[tx][ty + i * 8]);
    }
  }
}

// bP[4h+g] = bx[g*1024+h] + bh[g*1024+h]
__global__ __launch_bounds__(256) void bias_perm(const float* __restrict__ bx,
                                                 const float* __restrict__ bh,
                                                 float* __restrict__ bP) {
  const int n = blockIdx.x * 256 + threadIdx.x;
  if (n >= G4_) return;
  const int h = n >> 2, g = n & 3;
  bP[n] = bx[g * HID_ + h] + bh[g * HID_ + h];
}

extern "C" void kernel_launch(void* const* d_in, const int* in_sizes, int n_in,
                              void* d_out, int out_size, void* d_ws, size_t ws_size,
                              hipStream_t stream) {
  const int* X = (const int*)d_in[0];
  const float* C = (const float*)d_in[1];
  const float* Wx = (const float*)d_in[2];
  const float* bx = (const float*)d_in[3];
  const float* Wh = (const float*)d_in[4];
  const float* bh = (const float*)d_in[5];
  const float* Wo = (const float*)d_in[6];
  const float* bo = (const float*)d_in[7];
  float* out = (float*)d_out;

  char* p = (char*)d_ws;
  const size_t szCb  = (size_t)NCLS_ * EMB_ * 2;   // Cb, reused for Wot
  const size_t szWxt = (size_t)G4_ * EMB_ * 2;
  const size_t szBpk = (size_t)G4_ * HID_ * 2;     // packed Wh
  const size_t szEpr = (size_t)NCLS_ * G4_ * 2;
  const size_t szH   = (size_t)BATCH_ * HID_ * 2;  // x2: hA, hB
  const size_t szC   = (size_t)BATCH_ * HID_ * 4;
  const size_t szBp  = (size_t)G4_ * 4;
  if (ws_size < szCb + szWxt + szBpk + szEpr + 2 * szH + szC + szBp) return;

  __hip_bfloat16* Cb   = (__hip_bfloat16*)p; p += szCb;
  __hip_bfloat16* WxtP = (__hip_bfloat16*)p; p += szWxt;
  __hip_bfloat16* Bpk  = (__hip_bfloat16*)p; p += szBpk;
  __hip_bfloat16* Epr  = (__hip_bfloat16*)p; p += szEpr;
  __hip_bfloat16* hA   = (__hip_bfloat16*)p; p += szH;
  __hip_bfloat16* hB   = (__hip_bfloat16*)p; p += szH;
  float* cbuf          = (float*)p;          p += szC;
  float* bP            = (float*)p;          p += szBp;

  // 1. C -> bf16, k-swizzled (A operand of E_proj)
  {
    const int n4 = NCLS_ * EMB_ / 4;
    conv_bf16_k<true><<<(n4 + 255) / 256, 256, 0, stream>>>(C, Cb, n4);
  }
  // 2. Wx -> [4096][1024] gate-interleaved rows, k-swizzled (Bt of E_proj)
  transpose_conv<true, true><<<dim3(G4_ / 32, EMB_ / 32), dim3(32, 8), 0, stream>>>(
      Wx, WxtP, EMB_, G4_);
  // 3. Wh -> fragment-packed Bpk (step kernel's B)
  pack_b<<<2048, 256, 0, stream>>>(Wh, Bpk);
  // 4. permuted bias
  bias_perm<<<G4_ / 256, 256, 0, stream>>>(bx, bh, bP);

  // 5. Epr[V][4096] = C @ Wx + (bx+bh)
  gemm_bt<0><<<dim3(G4_ / 128, (NCLS_ + 127) / 128), 256, 0, stream>>>(
      Cb, WxtP, nullptr, Epr, NCLS_, G4_, EMB_, G4_, bP);

  // 6. zero initial state
  hipMemsetAsync(hA, 0, szH, stream);
  hipMemsetAsync(cbuf, 0, szC, stream);

  // 7. 128 fused LSTM steps (r7 config); final h lands in hA
  for (int t = 0; t < SEQ_; ++t) {
    const __hip_bfloat16* hp = (t & 1) ? hB : hA;
    __hip_bfloat16* hn = (t & 1) ? hA : hB;
    lstm_step<<<256, 512, 98304, stream>>>(hp, Bpk, Epr, X, cbuf, hn, t);
  }

  // 8. W_out^T, k-swizzled, into Cb region (dead after step 5)
  __hip_bfloat16* Wot = Cb;
  transpose_conv<false, true><<<dim3((NCLS_ + 31) / 32, HID_ / 32), dim3(32, 8), 0,
                                stream>>>(Wo, Wot, HID_, NCLS_);

  // 9. logits = hA @ W_out + b_out
  gemm_bt<2><<<dim3((NCLS_ + 127) / 128, BATCH_ / 128), 256, 0, stream>>>(
      hA, Wot, out, nullptr, BATCH_, NCLS_, HID_, NCLS_, bo);
}

// Round 19
// 2883.140 us; speedup vs baseline: 1.0469x; 1.0469x over previous
//
#include <hip/hip_runtime.h>
#include <hip/hip_bf16.h>

#define SEQ_   128
#define NCLS_  50257
#define EMB_   1024
#define HID_   1024
#define BATCH_ 1024
#define G4_    4096

typedef __attribute__((ext_vector_type(8))) short short8;
typedef __attribute__((ext_vector_type(4))) float f32x4;

__device__ __forceinline__ void async_copy16(void* lds, const void* g) {
  __builtin_amdgcn_global_load_lds(
      (const __attribute__((address_space(1))) void*)g,
      (__attribute__((address_space(3))) void*)lds, 16, 0, 0);
}

#define MFMA_ACC(c, a, b) \
  (c) = __builtin_amdgcn_mfma_f32_16x16x32_bf16((a), (b), (c), 0, 0, 0)

#define CFENCE() asm volatile("" ::: "memory")

__device__ __forceinline__ float sigmoidf_(float x) {
  return 1.f / (1.f + __expf(-x));
}
__device__ __forceinline__ float tanhf_(float x) {
  x = fminf(12.f, fmaxf(-12.f, x));
  float e = __expf(2.f * x);
  return (e - 1.f) / (e + 1.f);
}
__device__ __forceinline__ float bf2f_(ushort u) {
  return __uint_as_float(((unsigned int)u) << 16);
}

// ---------------------------------------------------------------------------
// MFMA GEMM (r4 structure, builtin MFMA): C = A[M,K] x Bt[N,K], k-XOR-
// swizzled rows, BK=64 double-buffered, counted vmcnt(8), 256 thr / 4 waves.
// EPI 0: outB = bf16(acc + bias0[col]); LDS-repacked epilogue (stride 136)
//        -> 16B/lane full-row stores.
// EPI 2: outF = acc + bias0[col]; LDS-repacked [64][132] f32 half-tiles
//        -> full-row coalesced dword stores.
// ---------------------------------------------------------------------------
template <int EPI>
__global__ __launch_bounds__(256) void gemm_bt(
    const __hip_bfloat16* __restrict__ A, const __hip_bfloat16* __restrict__ Bt,
    float* __restrict__ outF, __hip_bfloat16* __restrict__ outB,
    int Mreal, int Nreal, int K, long ostride,
    const float* __restrict__ bias0) {
  __shared__ __align__(16) char smem[65536];

  const int tid = threadIdx.x;
  const int lane = tid & 63;
  const int w = tid >> 6;
  const int wm = w >> 1;
  const int wn = w & 1;
  const int m0 = blockIdx.y * 128;
  const int n0 = blockIdx.x * 128;

  const int fr = lane & 15;
  const int kb = (lane >> 4) * 16;
  const int swz = (fr & 7) << 4;

  f32x4 acc[4][4];
#pragma unroll
  for (int i = 0; i < 4; ++i)
#pragma unroll
    for (int j = 0; j < 4; ++j) acc[i][j] = (f32x4)(0.0f);

  auto STAGE = [&](int kc, int b) {
#pragma unroll
    for (int q = 0; q < 8; ++q) {
      const int ridx = (q & 3) * 256 + tid;
      const int row = ridx >> 3;
      const int ch = ridx & 7;
      const __hip_bfloat16* src;
      char* dst;
      if (q < 4) {
        long ar = m0 + row; if (ar >= Mreal) ar = Mreal - 1;
        src = A + ar * (long)K + kc * 64 + ch * 8;
        dst = smem + b * 16384 + ridx * 16;
      } else {
        long br = n0 + row; if (br >= Nreal) br = Nreal - 1;
        src = Bt + br * (long)K + kc * 64 + ch * 8;
        dst = smem + 32768 + b * 16384 + ridx * 16;
      }
      async_copy16(dst, src);
    }
  };

  const int KC = K >> 6;
  STAGE(0, 0);
  for (int kc = 0; kc < KC; ++kc) {
    const int b = kc & 1;
    if (kc + 1 < KC) {
      STAGE(kc + 1, b ^ 1);
      asm volatile("s_waitcnt vmcnt(8)" ::: "memory");
    } else {
      asm volatile("s_waitcnt vmcnt(0)" ::: "memory");
    }
    __builtin_amdgcn_s_barrier();
    CFENCE();

    short8 aR[2][4], bR[2][4];
#pragma unroll
    for (int kk = 0; kk < 2; ++kk)
#pragma unroll
      for (int f = 0; f < 4; ++f) {
        aR[kk][f] = *(const short8*)(smem + b * 16384 +
                     (wm * 64 + f * 16 + fr) * 128 + ((kk * 64 + kb) ^ swz));
        bR[kk][f] = *(const short8*)(smem + 32768 + b * 16384 +
                     (wn * 64 + f * 16 + fr) * 128 + ((kk * 64 + kb) ^ swz));
      }
#pragma unroll
    for (int fm = 0; fm < 4; ++fm)
#pragma unroll
      for (int fn = 0; fn < 4; ++fn) {
        MFMA_ACC(acc[fm][fn], aR[0][fm], bR[0][fn]);
        MFMA_ACC(acc[fm][fn], aR[1][fm], bR[1][fn]);
      }
    CFENCE();
    __builtin_amdgcn_s_barrier();
  }

  const int cn = lane & 15;
  const int rb = (lane >> 4) * 4;

  if (EPI == 0) {
    __hip_bfloat16* ldsC = (__hip_bfloat16*)smem;  // [128][136] bf16
#pragma unroll
    for (int fn = 0; fn < 4; ++fn) {
      const int col = wn * 64 + fn * 16 + cn;
      const float badd = bias0[n0 + col];
#pragma unroll
      for (int fm = 0; fm < 4; ++fm)
#pragma unroll
        for (int r = 0; r < 4; ++r)
          ldsC[(wm * 64 + fm * 16 + rb + r) * 136 + col] =
              __float2bfloat16(acc[fm][fn][r] + badd);
    }
    __syncthreads();
#pragma unroll
    for (int q = 0; q < 8; ++q) {
      const int chunk = q * 256 + tid;      // 0..2047 (128 rows x 16 chunks)
      const int row = chunk >> 4;
      const int c8 = (chunk & 15) * 8;
      if (m0 + row < Mreal)
        *(short8*)(outB + (long)(m0 + row) * ostride + n0 + c8) =
            *(const short8*)(ldsC + row * 136 + c8);
    }
  } else {
    float* ldsC = (float*)smem;  // [64][132] f32
#pragma unroll
    for (int half = 0; half < 2; ++half) {
      __syncthreads();
      if (wm == half) {
#pragma unroll
        for (int fn = 0; fn < 4; ++fn) {
          const int col = wn * 64 + fn * 16 + cn;
          const int gc = n0 + col;
          const float badd = (gc < Nreal) ? bias0[gc] : 0.f;
#pragma unroll
          for (int fm = 0; fm < 4; ++fm)
#pragma unroll
            for (int r = 0; r < 4; ++r)
              ldsC[(fm * 16 + rb + r) * 132 + col] = acc[fm][fn][r] + badd;
        }
      }
      __syncthreads();
#pragma unroll
      for (int it = 0; it < 32; ++it) {
        const int idx = it * 256 + tid;   // 0..8191 (64 rows x 128 cols)
        const int row = idx >> 7;
        const int col = idx & 127;
        const int grow = m0 + half * 64 + row;
        const int gcol = n0 + col;
        if (grow < Mreal && gcol < Nreal)
          outF[(long)grow * ostride + gcol] = ldsC[row * 132 + col];
      }
    }
  }
}

// ---------------------------------------------------------------------------
// Wh pack (r7 layout): tile = ((ht*2+wn)*2+kh)*64 + kc*8 + kk*4 + g.
// ---------------------------------------------------------------------------
__global__ __launch_bounds__(256) void pack_b(const float* __restrict__ Wh,
                                              __hip_bfloat16* __restrict__ Bpk) {
  const int gtid = blockIdx.x * 256 + threadIdx.x;  // 0..524287
  const int l = gtid & 63;
  const int tile = gtid >> 6;                       // 0..8191
  const int g = tile & 3;
  const int kk = (tile >> 2) & 1;
  const int kc = (tile >> 3) & 7;
  const int kh = (tile >> 6) & 1;
  const int wn = (tile >> 7) & 1;
  const int ht = tile >> 8;
  const int h = ht * 32 + wn * 16 + (l & 15);
  const int k0 = kh * 512 + kc * 64 + kk * 32 + (l >> 4) * 8;
  short8 v;
#pragma unroll
  for (int e = 0; e < 8; ++e) {
    const __hip_bfloat16 b = __float2bfloat16(Wh[(size_t)(k0 + e) * G4_ + g * 1024 + h]);
    v[e] = *reinterpret_cast<const short*>(&b);
  }
  *(short8*)(Bpk + (size_t)gtid * 8) = v;
}

// ---------------------------------------------------------------------------
// Fused LSTM step (r7 structure, builtin MFMA). Grid 256, 512 threads,
// 96 KB dynamic LDS (3 x 32KB A bufs), B direct-to-register from Bpk.
// Eps/c loads issued POST-loop (r17 placement — r18's pre-loop prefetch
// regressed via register pressure).
// ---------------------------------------------------------------------------
__global__ __launch_bounds__(512, 2) void lstm_step(
    const __hip_bfloat16* __restrict__ hprev,   // [1024][1024] swizzled
    const __hip_bfloat16* __restrict__ Bpk,     // packed Wh (8 MB)
    const __hip_bfloat16* __restrict__ Epr,     // [V][4096] col=4h+g
    const int* __restrict__ X,
    float* __restrict__ cbuf,                   // [1024][1024] f32
    __hip_bfloat16* __restrict__ hnext,         // swizzled
    int t) {
  extern __shared__ __align__(16) char smem[];  // 98304 = 3 x 32KB A bufs
  float* gacc = (float*)smem;                   // [128][132] f32 (aliases)

  const int tid = threadIdx.x;
  const int lane = tid & 63;
  const int w = tid >> 6;
  const int wm = (w >> 1) & 1;
  const int wn = w & 1;
  const int kh = w >> 2;
  const int bid = blockIdx.x;
  const int xcd = bid & 7;
  const int j = bid >> 3;
  const int ht = xcd * 4 + (j & 3);   // Bpk slice pinned to one XCD's L2
  const int mt = j >> 2;
  const int m0 = mt * 128;
  const int h0 = ht * 32;

  const int fr = lane & 15;
  const int kb = (lane >> 4) * 16;
  const int swz = (fr & 7) << 4;
  const int cn = lane & 15;
  const int rb = (lane >> 4) * 4;

  const int crow = tid >> 2;
  const int hq = tid & 3;
  const int prow = m0 + crow;
  const int tok1 = X[prow * SEQ_ + t];

  const __hip_bfloat16* bb =
      Bpk + (size_t)(((ht * 2 + wn) * 2 + kh) * 64) * 512 + lane * 8;

  f32x4 acc[4][4];  // [fm][gate]
#pragma unroll
  for (int i = 0; i < 4; ++i)
#pragma unroll
    for (int g = 0; g < 4; ++g) acc[i][g] = (f32x4)(0.0f);

  auto STAGE_A = [&](int kc, int b) {
#pragma unroll
    for (int q = 0; q < 4; ++q) {
      const int region = q >> 1;           // kh-half
      const int r = (q & 1) * 512 + tid;   // 0..1023 chunks
      const int row = r >> 3, ch = r & 7;
      const __hip_bfloat16* src =
          hprev + (size_t)(m0 + row) * HID_ + region * 512 + kc * 64 + ch * 8;
      async_copy16(smem + b * 32768 + region * 16384 + r * 16, src);
    }
  };

  short8 bR[2][2][4];  // [kc&1][kk][g]

  STAGE_A(0, 0);
#pragma unroll
  for (int kk = 0; kk < 2; ++kk)
#pragma unroll
    for (int g = 0; g < 4; ++g)
      bR[0][kk][g] = *(const short8*)(bb + (0 * 8 + kk * 4 + g) * 512);
  STAGE_A(1, 1);

#pragma unroll
  for (int kc = 0; kc < 8; ++kc) {
    __builtin_amdgcn_s_barrier();
    CFENCE();
    if (kc + 1 < 8) {
#pragma unroll
      for (int kk = 0; kk < 2; ++kk)
#pragma unroll
        for (int g = 0; g < 4; ++g)
          bR[(kc + 1) & 1][kk][g] =
              *(const short8*)(bb + ((kc + 1) * 8 + kk * 4 + g) * 512);
    }
    if (kc + 2 < 8) STAGE_A(kc + 2, (kc + 2) % 3);
    if (kc < 6)      asm volatile("s_waitcnt vmcnt(24)" ::: "memory");
    else if (kc == 6) asm volatile("s_waitcnt vmcnt(20)" ::: "memory");
    else             asm volatile("s_waitcnt vmcnt(8)" ::: "memory");
    CFENCE();

    const char* baseA = smem + (kc % 3) * 32768 + kh * 16384;
    short8 aR[2][4];
#pragma unroll
    for (int kk = 0; kk < 2; ++kk)
#pragma unroll
      for (int f = 0; f < 4; ++f)
        aR[kk][f] = *(const short8*)(baseA + (wm * 64 + f * 16 + fr) * 128 +
                                     ((kk * 64 + kb) ^ swz));
    __builtin_amdgcn_s_setprio(1);
#pragma unroll
    for (int fm = 0; fm < 4; ++fm)
#pragma unroll
      for (int g = 0; g < 4; ++g) {
        MFMA_ACC(acc[fm][g], aR[0][fm], bR[kc & 1][0][g]);
        MFMA_ACC(acc[fm][g], aR[1][fm], bR[kc & 1][1][g]);
      }
    __builtin_amdgcn_s_setprio(0);
    CFENCE();
  }

  ushort4 ep[8];
  float cold[8];
#pragma unroll
  for (int jj = 0; jj < 8; ++jj) {
    ep[jj] = *(const ushort4*)(Epr + (size_t)tok1 * G4_ + (h0 + hq * 8 + jj) * 4);
    cold[jj] = cbuf[(size_t)prow * HID_ + h0 + hq * 8 + jj];
  }

  __syncthreads();
  if (kh == 0) {
#pragma unroll
    for (int fm = 0; fm < 4; ++fm)
#pragma unroll
      for (int g = 0; g < 4; ++g)
#pragma unroll
        for (int r = 0; r < 4; ++r)
          gacc[(wm * 64 + fm * 16 + rb + r) * 132 + (wn * 16 + cn) * 4 + g] =
              acc[fm][g][r];
  }
  __syncthreads();
  if (kh == 1) {
#pragma unroll
    for (int fm = 0; fm < 4; ++fm)
#pragma unroll
      for (int g = 0; g < 4; ++g)
#pragma unroll
        for (int r = 0; r < 4; ++r)
          gacc[(wm * 64 + fm * 16 + rb + r) * 132 + (wn * 16 + cn) * 4 + g] +=
              acc[fm][g][r];
  }
  __syncthreads();

  const float* gr = gacc + crow * 132 + hq * 32;
  f32x4 cnew0, cnew1;
  short8 hv;
#pragma unroll
  for (int jj = 0; jj < 8; ++jj) {
    const f32x4 g4 = *(const f32x4*)(gr + jj * 4);
    const float iv = sigmoidf_(g4[0] + bf2f_(ep[jj].x));
    const float fv = sigmoidf_(g4[1] + bf2f_(ep[jj].y));
    const float gv = tanhf_(g4[2] + bf2f_(ep[jj].z));
    const float ov = sigmoidf_(g4[3] + bf2f_(ep[jj].w));
    const float cv = fv * cold[jj] + iv * gv;
    if (jj < 4) cnew0[jj] = cv; else cnew1[jj - 4] = cv;
    const float hval = ov * tanhf_(cv);
    const __hip_bfloat16 hb = __float2bfloat16(hval);
    hv[jj] = *reinterpret_cast<const short*>(&hb);
  }
  float* cdst = cbuf + (size_t)prow * HID_ + h0 + hq * 8;
  *(f32x4*)cdst = cnew0;
  *(f32x4*)(cdst + 4) = cnew1;
  const int hcolb = h0 + hq * 8;
  const int hswb = (hcolb & ~63) | ((hcolb & 63) ^ ((prow & 7) << 3));
  *(short8*)(hnext + (size_t)prow * HID_ + hswb) = hv;
}

// fp32 -> bf16 flat convert; SWZ: k-XOR-swizzle per 64-col group (1024 cols)
template <bool SWZ>
__global__ __launch_bounds__(256) void conv_bf16_k(const float* __restrict__ in,
                                                   __hip_bfloat16* __restrict__ out, int n4) {
  const int i = blockIdx.x * 256 + threadIdx.x;
  if (i >= n4) return;
  const float4 v = ((const float4*)in)[i];
  int o = i * 4;
  if (SWZ) {
    const int row = o >> 10, col = o & 1023;
    const int cs = (col & ~63) | ((col & 63) ^ ((row & 7) << 3));
    o = (o & ~1023) | cs;
  }
  out[o + 0] = __float2bfloat16(v.x);
  out[o + 1] = __float2bfloat16(v.y);
  out[o + 2] = __float2bfloat16(v.z);
  out[o + 3] = __float2bfloat16(v.w);
}

// in[R][C] fp32 -> out[C][R] bf16; PERM: gate-interleave out-rows (4h+g);
// SWZ: XOR-swizzle k per 64-group by out-row&7.
template <bool PERM, bool SWZ>
__global__ __launch_bounds__(256) void transpose_conv(const float* __restrict__ in,
                                                      __hip_bfloat16* __restrict__ out,
                                                      int R, int C) {
  __shared__ float tile[32][33];
  const int c0 = blockIdx.x * 32, r0 = blockIdx.y * 32;
  const int tx = threadIdx.x, ty = threadIdx.y;  // 32x8
#pragma unroll
  for (int i = 0; i < 4; ++i) {
    const int r = r0 + ty + i * 8, cc = c0 + tx;
    tile[ty + i * 8][tx] = (r < R && cc < C) ? in[(size_t)r * C + cc] : 0.f;
  }
  __syncthreads();
#pragma unroll
  for (int i = 0; i < 4; ++i) {
    const int ro = c0 + ty + i * 8, co = r0 + tx;
    if (ro < C && co < R) {
      const int n = PERM ? ((ro & 1023) * 4 + (ro >> 10)) : ro;
      int k = co;
      if (SWZ) k = (k & ~63) | ((k & 63) ^ ((n & 7) << 3));
      out[(size_t)n * R + k] = __float2bfloat16(tile[tx][ty + i * 8]);
    }
  }
}

// bP[4h+g] = bx[g*1024+h] + bh[g*1024+h]
__global__ __launch_bounds__(256) void bias_perm(const float* __restrict__ bx,
                                                 const float* __restrict__ bh,
                                                 float* __restrict__ bP) {
  const int n = blockIdx.x * 256 + threadIdx.x;
  if (n >= G4_) return;
  const int h = n >> 2, g = n & 3;
  bP[n] = bx[g * HID_ + h] + bh[g * HID_ + h];
}

extern "C" void kernel_launch(void* const* d_in, const int* in_sizes, int n_in,
                              void* d_out, int out_size, void* d_ws, size_t ws_size,
                              hipStream_t stream) {
  const int* X = (const int*)d_in[0];
  const float* C = (const float*)d_in[1];
  const float* Wx = (const float*)d_in[2];
  const float* bx = (const float*)d_in[3];
  const float* Wh = (const float*)d_in[4];
  const float* bh = (const float*)d_in[5];
  const float* Wo = (const float*)d_in[6];
  const float* bo = (const float*)d_in[7];
  float* out = (float*)d_out;

  char* p = (char*)d_ws;
  const size_t szCb  = (size_t)NCLS_ * EMB_ * 2;   // Cb, reused for Wot
  const size_t szWxt = (size_t)G4_ * EMB_ * 2;
  const size_t szBpk = (size_t)G4_ * HID_ * 2;     // packed Wh
  const size_t szEpr = (size_t)NCLS_ * G4_ * 2;
  const size_t szH   = (size_t)BATCH_ * HID_ * 2;  // x2: hA, hB
  const size_t szC   = (size_t)BATCH_ * HID_ * 4;
  const size_t szBp  = (size_t)G4_ * 4;
  if (ws_size < szCb + szWxt + szBpk + szEpr + 2 * szH + szC + szBp) return;

  __hip_bfloat16* Cb   = (__hip_bfloat16*)p; p += szCb;
  __hip_bfloat16* WxtP = (__hip_bfloat16*)p; p += szWxt;
  __hip_bfloat16* Bpk  = (__hip_bfloat16*)p; p += szBpk;
  __hip_bfloat16* Epr  = (__hip_bfloat16*)p; p += szEpr;
  __hip_bfloat16* hA   = (__hip_bfloat16*)p; p += szH;
  __hip_bfloat16* hB   = (__hip_bfloat16*)p; p += szH;
  float* cbuf          = (float*)p;          p += szC;
  float* bP            = (float*)p;          p += szBp;

  // 1. C -> bf16, k-swizzled (A operand of E_proj)
  {
    const int n4 = NCLS_ * EMB_ / 4;
    conv_bf16_k<true><<<(n4 + 255) / 256, 256, 0, stream>>>(C, Cb, n4);
  }
  // 2. Wx -> [4096][1024] gate-interleaved rows, k-swizzled (Bt of E_proj)
  transpose_conv<true, true><<<dim3(G4_ / 32, EMB_ / 32), dim3(32, 8), 0, stream>>>(
      Wx, WxtP, EMB_, G4_);
  // 3. Wh -> fragment-packed Bpk (step kernel's B)
  pack_b<<<2048, 256, 0, stream>>>(Wh, Bpk);
  // 4. permuted bias
  bias_perm<<<G4_ / 256, 256, 0, stream>>>(bx, bh, bP);

  // 5. Epr[V][4096] = C @ Wx + (bx+bh)
  gemm_bt<0><<<dim3(G4_ / 128, (NCLS_ + 127) / 128), 256, 0, stream>>>(
      Cb, WxtP, nullptr, Epr, NCLS_, G4_, EMB_, G4_, bP);

  // 6. zero initial state
  hipMemsetAsync(hA, 0, szH, stream);
  hipMemsetAsync(cbuf, 0, szC, stream);

  // 7. 128 fused LSTM steps (r7 config); final h lands in hA
  for (int t = 0; t < SEQ_; ++t) {
    const __hip_bfloat16* hp = (t & 1) ? hB : hA;
    __hip_bfloat16* hn = (t & 1) ? hA : hB;
    lstm_step<<<256, 512, 98304, stream>>>(hp, Bpk, Epr, X, cbuf, hn, t);
  }

  // 8. W_out^T, k-swizzled, into Cb region (dead after step 5)
  __hip_bfloat16* Wot = Cb;
  transpose_conv<false, true><<<dim3((NCLS_ + 31) / 32, HID_ / 32), dim3(32, 8), 0,
                                stream>>>(Wo, Wot, HID_, NCLS_);

  // 9. logits = hA @ W_out + b_out
  gemm_bt<2><<<dim3((NCLS_ + 127) / 128, BATCH_ / 128), 256, 0, stream>>>(
      hA, Wot, out, nullptr, BATCH_, NCLS_, HID_, NCLS_, bo);
}